// Round 3
// baseline (31856.494 us; speedup 1.0000x reference)
//
#include <hip/hip_runtime.h>
#include <hip/hip_bf16.h>
#include <math.h>

namespace {

using bf16 = __hip_bfloat16;

constexpr int N_ = 65536, E_ = 262144, G_ = 1024, M_ = 64;
constexpr int D_ = 512, H_ = 8, C_ = 64, ED_ = 128, P_ = 1024, L_ = 5;
constexpr float SLOPE = 0.2f;
constexpr float EPSF = 1.1920929e-7f;   // finfo(float32).eps

constexpr int ECH = 8;                  // edge chunks
constexpr int ECHUNK = E_ / ECH;        // 32768 edges/chunk
constexpr int NCH = 8;                  // FFN row chunks
constexpr int NCHUNK = N_ / NCH;        // 8192 rows/chunk

__device__ inline float b2f(bf16 h) { return __bfloat162float(h); }
__device__ inline bf16 f2b(float f) { return __float2bfloat16(f); }
__device__ inline float us2f(unsigned short u) {
  return __uint_as_float((unsigned)u << 16);
}

// ---- ordered-uint encoding for float atomicMax ----
__device__ inline unsigned enc_f(float f) {
  unsigned u = __float_as_uint(f);
  return (u & 0x80000000u) ? ~u : (u | 0x80000000u);
}
__device__ inline float dec_f(unsigned e) {
  return (e & 0x80000000u) ? __uint_as_float(e & 0x7FFFFFFFu)
                           : __uint_as_float(~e);
}

// ================= GEMM: C[M,Nc] = A[M,K] @ B[K,Nc] + bias, optional GELU ====
// 64x64 tile, 256 threads, 4x4 microtile. M%64==0, Nc%64==0, K%16==0 (all hold).
// A is fp32 or bf16 (converted to fp32 in LDS); B/bias fp32; C fp32 or bf16.
template <int EPI, typename TIN, typename TOUT>  // EPI: 0 none, 1 exact gelu
__global__ __launch_bounds__(256) void gemm_bias_k(
    const TIN* __restrict__ A, const float* __restrict__ B,
    const float* __restrict__ bias, TOUT* __restrict__ C,
    int M, int K, int Nc) {
  __shared__ float As[64][17];
  __shared__ float Bs[16][68];
  const int tid = threadIdx.x;
  const int m0 = blockIdx.x * 64;
  const int n0 = blockIdx.y * 64;
  const int ty = tid >> 4, tx = tid & 15;
  const int lam = tid >> 2;           // A-load row within tile
  const int lak = (tid & 3) << 2;     // A-load k offset
  const int lbk = tid >> 4;           // B-load k row
  const int lbn = (tid & 15) << 2;    // B-load n offset
  const TIN* Aptr = A + (long)(m0 + lam) * K + lak;
  const float* Bptr = B + (long)lbk * Nc + n0 + lbn;
  float acc[4][4] = {};
  for (int kt = 0; kt < K; kt += 16) {
    float4 va;
    if (sizeof(TIN) == 2) {
      ushort4 u = *(const ushort4*)(Aptr + kt);
      va.x = us2f(u.x); va.y = us2f(u.y); va.z = us2f(u.z); va.w = us2f(u.w);
    } else {
      va = *(const float4*)(Aptr + kt);
    }
    float4 vb = *(const float4*)(Bptr + (long)kt * Nc);
    __syncthreads();
    As[lam][lak + 0] = va.x; As[lam][lak + 1] = va.y;
    As[lam][lak + 2] = va.z; As[lam][lak + 3] = va.w;
    Bs[lbk][lbn + 0] = vb.x; Bs[lbk][lbn + 1] = vb.y;
    Bs[lbk][lbn + 2] = vb.z; Bs[lbk][lbn + 3] = vb.w;
    __syncthreads();
#pragma unroll
    for (int kk = 0; kk < 16; ++kk) {
      float a[4], b[4];
#pragma unroll
      for (int i = 0; i < 4; ++i) a[i] = As[ty * 4 + i][kk];
#pragma unroll
      for (int j = 0; j < 4; ++j) b[j] = Bs[kk][tx * 4 + j];
#pragma unroll
      for (int i = 0; i < 4; ++i)
#pragma unroll
        for (int j = 0; j < 4; ++j) acc[i][j] = fmaf(a[i], b[j], acc[i][j]);
    }
  }
#pragma unroll
  for (int i = 0; i < 4; ++i) {
    long row = (long)(m0 + ty * 4 + i) * Nc + n0;
#pragma unroll
    for (int j = 0; j < 4; ++j) {
      float c = acc[i][j] + (bias ? bias[n0 + tx * 4 + j] : 0.f);
      if (EPI == 1) c = 0.5f * c * (1.f + erff(c * 0.70710678118654752f));
      if (sizeof(TOUT) == 2)
        ((bf16*)C)[row + tx * 4 + j] = f2b(c);
      else
        ((float*)C)[row + tx * 4 + j] = c;
    }
  }
}

// ================= encoders =================
__global__ __launch_bounds__(256) void encode_nodes_k(
    const int* __restrict__ nodeX, const float* __restrict__ atomEmb,
    bf16* __restrict__ x) {
  int n = blockIdx.x, tid = threadIdx.x;
  __shared__ int idx[9];
  if (tid < 9) idx[tid] = nodeX[n * 9 + tid];
  __syncthreads();
  for (int d = tid; d < D_; d += 256) {
    float s = 0.f;
#pragma unroll
    for (int k = 0; k < 9; ++k) s += atomEmb[(k * 119 + idx[k]) * D_ + d];
    x[(long)n * D_ + d] = f2b(s);
  }
}

// one chunk of edge-attr embeddings: eattr_chunk[e,d], e in [0,ECHUNK)
__global__ __launch_bounds__(128) void encode_edges_k(
    const int* __restrict__ eai, const float* __restrict__ edgeEmb,
    bf16* __restrict__ eattr) {
  int e = blockIdx.x, tid = threadIdx.x;
  __shared__ int idx[3];
  if (tid < 3) idx[tid] = eai[e * 3 + tid];
  __syncthreads();
  float s = 0.f;
#pragma unroll
  for (int k = 0; k < 3; ++k) s += edgeEmb[(k * 22 + idx[k]) * ED_ + tid];
  eattr[(long)e * ED_ + tid] = f2b(s);
}

// ================= per-layer init =================
__global__ void init_md_k(unsigned* __restrict__ mx, float* __restrict__ denom) {
  int id = blockIdx.x * 256 + threadIdx.x;  // N*H
  mx[id] = 0x007FFFFFu;  // enc(-inf)
  denom[id] = 0.f;
}
__global__ void init_xa_k(float* __restrict__ xa, const float* __restrict__ gb) {
  long id = (long)blockIdx.x * 256 + threadIdx.x;  // N*D
  xa[id] = gb[(int)(id & (D_ - 1))];
}

// ================= GATv2 edge pipeline =================
// logits[e,h] = sum_c leaky(xl[src]+xr[dst]+ee[e]) * att[h,c]; also atomicMax.
// Operates on one edge chunk: src/dst/logits pre-offset, ee chunk-local.
__global__ __launch_bounds__(256) void edge_logits_k(
    const bf16* __restrict__ xl, const bf16* __restrict__ xr,
    const bf16* __restrict__ ee, const float* __restrict__ att,
    const int* __restrict__ src, const int* __restrict__ dst,
    float* __restrict__ logits, unsigned* __restrict__ mx) {
  int e = blockIdx.x;
  int s = src[e], t = dst[e];
  int tid = threadIdx.x;
  int h = tid >> 5, c0 = tid & 31;
  __shared__ float red[256];
  float p = 0.f;
#pragma unroll
  for (int q = 0; q < 2; ++q) {
    int d = h * C_ + c0 + q * 32;
    float v = b2f(xl[(long)s * D_ + d]) + b2f(xr[(long)t * D_ + d]) +
              b2f(ee[(long)e * D_ + d]);
    v = (v > 0.f) ? v : SLOPE * v;
    p += v * att[d];
  }
  red[tid] = p;
  __syncthreads();
  for (int off = 16; off > 0; off >>= 1) {
    if ((tid & 31) < off) red[tid] += red[tid + off];
    __syncthreads();
  }
  if ((tid & 31) == 0) {
    float lg = red[tid];
    logits[(long)e * H_ + h] = lg;
    atomicMax(&mx[(long)t * H_ + h], enc_f(lg));
  }
}

__global__ __launch_bounds__(256) void edge_p_k(
    float* __restrict__ logits, const unsigned* __restrict__ mx,
    const int* __restrict__ dst, float* __restrict__ denom) {
  int id = blockIdx.x * 256 + threadIdx.x;  // E*H
  int e = id >> 3, h = id & 7;
  int t = dst[e];
  float p = expf(logits[id] - dec_f(mx[t * H_ + h]));
  logits[id] = p;
  atomicAdd(denom + t * H_ + h, p);
}

__global__ __launch_bounds__(256) void edge_alpha_k(
    float* __restrict__ logits, const float* __restrict__ denom,
    const int* __restrict__ dst) {
  int id = blockIdx.x * 256 + threadIdx.x;  // E*H
  int e = id >> 3, h = id & 7;
  logits[id] /= denom[dst[e] * H_ + h];
}

__global__ __launch_bounds__(256) void edge_scatter_k(
    const bf16* __restrict__ xl, const float* __restrict__ alpha,
    const int* __restrict__ src, const int* __restrict__ dst,
    float* __restrict__ xa) {
  long id = (long)blockIdx.x * 256 + threadIdx.x;  // E*D
  int e = (int)(id >> 9), d = (int)(id & 511);
  int h = d >> 6;
  float a = alpha[(long)e * H_ + h];
  atomicAdd(xa + (long)dst[e] * D_ + d, b2f(xl[(long)src[e] * D_ + d]) * a);
}

// ================= rmsnorm(x + xa), x bf16 in/out =================
__global__ __launch_bounds__(256) void rmsnorm_res_k(
    bf16* __restrict__ x, const float* __restrict__ xa,
    const float* __restrict__ w) {
  int n = blockIdx.x, tid = threadIdx.x;
  long base = (long)n * D_;
  float v0 = b2f(x[base + tid]) + xa[base + tid];
  float v1 = b2f(x[base + tid + 256]) + xa[base + tid + 256];
  float ss = v0 * v0 + v1 * v1;
#pragma unroll
  for (int o = 32; o > 0; o >>= 1) ss += __shfl_xor(ss, o);
  __shared__ float wsum[4];
  if ((tid & 63) == 0) wsum[tid >> 6] = ss;
  __syncthreads();
  float tot = wsum[0] + wsum[1] + wsum[2] + wsum[3];
  float scale = rsqrtf(tot * (1.0f / D_) + EPSF);
  x[base + tid] = f2b(v0 * scale * w[tid]);
  x[base + tid + 256] = f2b(v1 * scale * w[tid + 256]);
}

// ================= batch bookkeeping =================
__global__ void zero_int_k(int* __restrict__ p) {
  p[blockIdx.x * 256 + threadIdx.x] = 0;
}
__global__ void count_k(const int* __restrict__ batch, int* __restrict__ counts) {
  int id = blockIdx.x * 256 + threadIdx.x;  // N
  atomicAdd(&counts[batch[id]], 1);
}
__global__ void scan_k(const int* __restrict__ counts, int* __restrict__ starts) {
  __shared__ int buf[G_];
  int t = threadIdx.x;
  int c = counts[t];
  buf[t] = c;
  __syncthreads();
  for (int off = 1; off < G_; off <<= 1) {
    int v = (t >= off) ? buf[t - off] : 0;
    __syncthreads();
    buf[t] += v;
    __syncthreads();
  }
  starts[t] = buf[t] - c;  // exclusive
}

// ================= attention pooling (z is bf16) =================
__global__ __launch_bounds__(256) void pool_k(
    const bf16* __restrict__ z, const float* __restrict__ avW,
    const float* __restrict__ avb, const int* __restrict__ counts,
    const int* __restrict__ starts, float* __restrict__ hg) {
  int g = blockIdx.x, tid = threadIdx.x;
  int cnt = counts[g], st = starts[g];
  __shared__ float aL[M_];
  int wave = tid >> 6, lane = tid & 63;
  for (int m = wave; m < M_; m += 4) {
    float s = 0.f;
    if (m < cnt) {
      const bf16* row = z + (long)(st + m) * D_;
      for (int c = lane; c < D_; c += 64) s += b2f(row[c]) * avW[c];
    }
#pragma unroll
    for (int o = 32; o > 0; o >>= 1) s += __shfl_xor(s, o);
    if (lane == 0) aL[m] = s;
  }
  __syncthreads();
  if (tid < 64) {
    float v = (tid < cnt) ? aL[tid] + avb[0] : -__builtin_inff();
    float mxv = v;
#pragma unroll
    for (int o = 32; o > 0; o >>= 1) mxv = fmaxf(mxv, __shfl_xor(mxv, o));
    float p = (tid < cnt) ? expf(v - mxv) : 0.f;
    float sm = p;
#pragma unroll
    for (int o = 32; o > 0; o >>= 1) sm += __shfl_xor(sm, o);
    aL[tid] = p / sm;
  }
  __syncthreads();
  for (int d = tid; d < D_; d += 256) {
    float acc = 0.f;
    for (int m = 0; m < cnt; ++m) acc += b2f(z[(long)(st + m) * D_ + d]) * aL[m];
    hg[(long)g * D_ + d] = acc;
  }
}

// hp = relu(rmsnorm(in, w)), row length P (all fp32)
__global__ __launch_bounds__(256) void rms_relu_k(
    const float* __restrict__ in, const float* __restrict__ w,
    float* __restrict__ out) {
  int g = blockIdx.x, tid = threadIdx.x;
  long base = (long)g * P_;
  float v[4], ss = 0.f;
#pragma unroll
  for (int k = 0; k < 4; ++k) {
    v[k] = in[base + tid + k * 256];
    ss += v[k] * v[k];
  }
#pragma unroll
  for (int o = 32; o > 0; o >>= 1) ss += __shfl_xor(ss, o);
  __shared__ float wsum[4];
  if ((tid & 63) == 0) wsum[tid >> 6] = ss;
  __syncthreads();
  float tot = wsum[0] + wsum[1] + wsum[2] + wsum[3];
  float scale = rsqrtf(tot * (1.0f / P_) + EPSF);
#pragma unroll
  for (int k = 0; k < 4; ++k) {
    float c = v[k] * scale * w[tid + k * 256];
    out[base + tid + k * 256] = fmaxf(c, 0.f);
  }
}

// ================= final outputs =================
// NOTE: out1 doubled as the xa accumulator during layers; fully overwritten here.
__global__ __launch_bounds__(256) void write_dense_k(
    const bf16* __restrict__ x, const int* __restrict__ counts,
    const int* __restrict__ starts, float* __restrict__ out1) {
  long id = (long)blockIdx.x * 256 + threadIdx.x;  // G*M*D
  int g = (int)(id >> 15);            // M*D = 32768
  int rem = (int)(id & 32767);
  int m = rem >> 9, d = rem & 511;
  float v = 0.f;
  if (m < counts[g]) v = b2f(x[(long)(starts[g] + m) * D_ + d]);
  out1[id] = v;
}
__global__ void write_mask_k(const int* __restrict__ counts,
                             float* __restrict__ out2) {
  int id = blockIdx.x * 256 + threadIdx.x;  // G*M
  out2[id] = ((id & 63) < counts[id >> 6]) ? 1.f : 0.f;
}

}  // namespace

extern "C" void kernel_launch(void* const* d_in, const int* in_sizes, int n_in,
                              void* d_out, int out_size, void* d_ws,
                              size_t ws_size, hipStream_t stream) {
  const int* node_x = (const int*)d_in[0];
  const int* edge_attr_idx = (const int*)d_in[1];
  const int* edge_index = (const int*)d_in[2];
  const int* batch = (const int*)d_in[3];
  const float* atom_emb = (const float*)d_in[4];
  const float* edge_emb = (const float*)d_in[5];
  const float* Wl = (const float*)d_in[6];
  const float* bl = (const float*)d_in[7];
  const float* Wr = (const float*)d_in[8];
  const float* br = (const float*)d_in[9];
  const float* We = (const float*)d_in[10];
  const float* att = (const float*)d_in[11];
  const float* gb = (const float*)d_in[12];
  const float* n1w = (const float*)d_in[13];
  const float* f1w = (const float*)d_in[14];
  const float* f1b = (const float*)d_in[15];
  const float* f2w = (const float*)d_in[16];
  const float* f2b = (const float*)d_in[17];
  const float* n2w = (const float*)d_in[18];
  const float* gapW = (const float*)d_in[19];
  const float* gapb = (const float*)d_in[20];
  const float* avW = (const float*)d_in[21];
  const float* avb = (const float*)d_in[22];
  const float* p1W = (const float*)d_in[23];
  const float* p1b = (const float*)d_in[24];
  const float* pnw = (const float*)d_in[25];
  const float* p2W = (const float*)d_in[26];
  const float* p2b = (const float*)d_in[27];
  const int* src = edge_index;
  const int* dst = edge_index + E_;

  // ---- workspace layout, peak ~254 MB (bf16 trunk) ----
  char* ws = (char*)d_ws;
  bf16* x = (bf16*)ws;                                   // N*D bf16
  bf16* xl = x + (long)N_ * D_;                          // N*D bf16
  bf16* xr = xl + (long)N_ * D_;                         // N*D bf16
  bf16* eebuf = xr + (long)N_ * D_;   // max(ECHUNK*D, NCHUNK*4D) bf16 (alias)
  bf16* echunk = eebuf + (long)ECHUNK * D_;              // ECHUNK*ED bf16
  float* logits = (float*)(echunk + (long)ECHUNK * ED_); // E*H fp32
  unsigned* mx = (unsigned*)(logits + (long)E_ * H_);    // N*H
  float* denom = (float*)(mx + (long)N_ * H_);           // N*H
  int* counts = (int*)(denom + (long)N_ * H_);           // G
  int* starts = counts + G_;                             // G
  float* hg = (float*)(starts + G_);                     // G*D fp32
  float* tmpP = hg + (long)G_ * D_;                      // G*P fp32
  float* hp = tmpP + (long)G_ * P_;                      // G*P fp32
  bf16* hid = eebuf;                                     // NCHUNK*4D alias

  float* out0 = (float*)d_out;                 // [G,P]
  float* out1 = out0 + (long)G_ * P_;          // [G,M,D]
  float* out2 = out1 + (long)G_ * M_ * D_;     // [G,M] mask as 0/1 float
  float* xa = out1;  // xa accumulator aliases out1 (dead before write_dense_k)

  encode_nodes_k<<<N_, 256, 0, stream>>>(node_x, atom_emb, x);

  for (int l = 0; l < L_; ++l) {
    const float* Wl_l = Wl + (long)l * D_ * D_;
    const float* bl_l = bl + (long)l * D_;
    const float* Wr_l = Wr + (long)l * D_ * D_;
    const float* br_l = br + (long)l * D_;
    const float* We_l = We + (long)l * ED_ * D_;
    const float* att_l = att + (long)l * H_ * C_;
    const float* gb_l = gb + (long)l * D_;
    const float* n1w_l = n1w + (long)l * D_;
    const float* f1w_l = f1w + (long)l * D_ * 4 * D_;
    const float* f1b_l = f1b + (long)l * 4 * D_;
    const float* f2w_l = f2w + (long)l * 4 * D_ * D_;
    const float* f2b_l = f2b + (long)l * D_;
    const float* n2w_l = n2w + (long)l * D_;

    gemm_bias_k<0, bf16, bf16><<<dim3(N_ / 64, D_ / 64), 256, 0, stream>>>(
        x, Wl_l, bl_l, xl, N_, D_, D_);
    gemm_bias_k<0, bf16, bf16><<<dim3(N_ / 64, D_ / 64), 256, 0, stream>>>(
        x, Wr_l, br_l, xr, N_, D_, D_);
    init_md_k<<<(N_ * H_) / 256, 256, 0, stream>>>(mx, denom);
    init_xa_k<<<(N_ * D_) / 256, 256, 0, stream>>>(xa, gb_l);

    // edge logits, chunked over E to bound the ee buffer
    for (int ec = 0; ec < ECH; ++ec) {
      long ebase = (long)ec * ECHUNK;
      encode_edges_k<<<ECHUNK, 128, 0, stream>>>(
          edge_attr_idx + ebase * 3, edge_emb, echunk);
      gemm_bias_k<0, bf16, bf16>
          <<<dim3(ECHUNK / 64, D_ / 64), 256, 0, stream>>>(
              echunk, We_l, nullptr, eebuf, ECHUNK, ED_, D_);
      edge_logits_k<<<ECHUNK, 256, 0, stream>>>(
          xl, xr, eebuf, att_l, src + ebase, dst + ebase,
          logits + ebase * H_, mx);
    }
    edge_p_k<<<(E_ * H_) / 256, 256, 0, stream>>>(logits, mx, dst, denom);
    edge_alpha_k<<<(E_ * H_) / 256, 256, 0, stream>>>(logits, denom, dst);
    edge_scatter_k<<<(int)(((long)E_ * D_) / 256), 256, 0, stream>>>(
        xl, logits, src, dst, xa);
    rmsnorm_res_k<<<N_, 256, 0, stream>>>(x, xa, n1w_l);

    // FFN, chunked over rows to bound the hidden buffer
    for (int nc = 0; nc < NCH; ++nc) {
      long nbase = (long)nc * NCHUNK;
      gemm_bias_k<1, bf16, bf16>
          <<<dim3(NCHUNK / 64, (4 * D_) / 64), 256, 0, stream>>>(
              x + nbase * D_, f1w_l, f1b_l, hid, NCHUNK, D_, 4 * D_);
      gemm_bias_k<0, bf16, float>
          <<<dim3(NCHUNK / 64, D_ / 64), 256, 0, stream>>>(
              hid, f2w_l, f2b_l, xa + nbase * D_, NCHUNK, 4 * D_, D_);
    }
    rmsnorm_res_k<<<N_, 256, 0, stream>>>(x, xa, n2w_l);
  }

  // batch bookkeeping (generic for sorted batch)
  zero_int_k<<<G_ / 256, 256, 0, stream>>>(counts);
  count_k<<<N_ / 256, 256, 0, stream>>>(batch, counts);
  scan_k<<<1, G_, 0, stream>>>(counts, starts);

  // pooling head: z into xl (free after layers)
  gemm_bias_k<0, bf16, bf16><<<dim3(N_ / 64, D_ / 64), 256, 0, stream>>>(
      x, gapW, gapb, xl, N_, D_, D_);
  pool_k<<<G_, 256, 0, stream>>>(xl, avW, avb, counts, starts, hg);
  gemm_bias_k<0, float, float><<<dim3(G_ / 64, P_ / 64), 256, 0, stream>>>(
      hg, p1W, p1b, tmpP, G_, D_, P_);
  rms_relu_k<<<G_, 256, 0, stream>>>(tmpP, pnw, hp);
  gemm_bias_k<0, float, float><<<dim3(G_ / 64, P_ / 64), 256, 0, stream>>>(
      hp, p2W, p2b, out0, G_, P_, P_);

  write_dense_k<<<(int)(((long)G_ * M_ * D_) / 256), 256, 0, stream>>>(
      x, counts, starts, out1);
  write_mask_k<<<(G_ * M_) / 256, 256, 0, stream>>>(counts, out2);
}